// Round 1
// baseline (3395.977 us; speedup 1.0000x reference)
//
#include <hip/hip_runtime.h>

#define NPAD 256
#define LDSX 1536

// Sum across 64 lanes via DPP; valid result lands in lane 63. Pure VALU.
__device__ __forceinline__ float wredf(float x) {
  x += __int_as_float(__builtin_amdgcn_update_dpp(0, __float_as_int(x), 0x111, 0xf, 0xf, true)); // row_shr:1
  x += __int_as_float(__builtin_amdgcn_update_dpp(0, __float_as_int(x), 0x112, 0xf, 0xf, true)); // row_shr:2
  x += __int_as_float(__builtin_amdgcn_update_dpp(0, __float_as_int(x), 0x114, 0xf, 0xf, true)); // row_shr:4
  x += __int_as_float(__builtin_amdgcn_update_dpp(0, __float_as_int(x), 0x118, 0xf, 0xf, true)); // row_shr:8
  x += __int_as_float(__builtin_amdgcn_update_dpp(0, __float_as_int(x), 0x142, 0xa, 0xf, true)); // bcast15 rows 1,3
  x += __int_as_float(__builtin_amdgcn_update_dpp(0, __float_as_int(x), 0x143, 0xc, 0xf, true)); // bcast31 rows 2,3
  return x;
}
__device__ __forceinline__ int wredi(int x) {
  x += __builtin_amdgcn_update_dpp(0, x, 0x111, 0xf, 0xf, true);
  x += __builtin_amdgcn_update_dpp(0, x, 0x112, 0xf, 0xf, true);
  x += __builtin_amdgcn_update_dpp(0, x, 0x114, 0xf, 0xf, true);
  x += __builtin_amdgcn_update_dpp(0, x, 0x118, 0xf, 0xf, true);
  x += __builtin_amdgcn_update_dpp(0, x, 0x142, 0xa, 0xf, true);
  x += __builtin_amdgcn_update_dpp(0, x, 0x143, 0xc, 0xf, true);
  return x;
}

// Block = one (n, di, diff). 256 threads = 4 waves; each wave handles 8 groups,
// all 64 lanes cover 64 consecutive t positions per iteration (16 iters over 1024).
__global__ void __launch_bounds__(256) hydra_kernel(
    const float* __restrict__ X, const float* __restrict__ W,
    float* __restrict__ out) {
  __shared__ float xs[LDSX];

  const int b = blockIdx.x;
  const int n = b / 14;
  const int r = b - n * 14;          // di*2 + diff
  const int diff = r & 1;
  const int d = 1 << (r >> 1);       // dilation
  const int Lz = 1024 - diff;        // output length (1023 for diff branch)
  const float* xrow = X + n * 1024;
  const int tid = threadIdx.x;

  // Stage padded input row (zeros in [0,256) and [256+Lz,1536))
  for (int i = tid; i < LDSX; i += 256) {
    int t = i - NPAD;
    float v = 0.0f;
    if (t >= 0 && t < Lz) v = diff ? (xrow[t + 1] - xrow[t]) : xrow[t];
    xs[i] = v;
  }
  __syncthreads();

  const int lane = tid & 63;
  const int wv = tid >> 6;
  const float* wb = W + r * 2304;                    // (di,diff) filter bank: 256*9
  float* outb = out + (size_t)n * 7168 + r * 512;    // [cmax(256) | cmin(256)]

  for (int gp = 0; gp < 8; ++gp) {
    const int g = wv * 8 + gp;

    // 72 wave-uniform weights for this group's 8 kernels
    float w[8][9];
    #pragma unroll
    for (int k = 0; k < 8; ++k)
      #pragma unroll
      for (int j = 0; j < 9; ++j)
        w[k][j] = wb[(g * 8 + k) * 9 + j];

    float cmax[8];
    int cmin[8];
    #pragma unroll
    for (int k = 0; k < 8; ++k) { cmax[k] = 0.0f; cmin[k] = 0; }

    const int base0 = NPAD - 4 * d + lane;           // index of tap 0 at t=lane

    #pragma unroll
    for (int it = 0; it < 16; ++it) {
      const int t = it * 64 + lane;

      float xv[9];
      #pragma unroll
      for (int j = 0; j < 9; ++j) xv[j] = xs[base0 + it * 64 + j * d];

      float z[8];
      #pragma unroll
      for (int k = 0; k < 8; ++k) {
        float a = w[k][0] * xv[0];
        #pragma unroll
        for (int j = 1; j < 9; ++j) a = fmaf(w[k][j], xv[j], a);
        z[k] = a;
      }

      const float mx = fmaxf(fmaxf(fmaxf(z[0], z[1]), fmaxf(z[2], z[3])),
                             fmaxf(fmaxf(z[4], z[5]), fmaxf(z[6], z[7])));
      const float mn = fminf(fminf(fminf(z[0], z[1]), fminf(z[2], z[3])),
                             fminf(fminf(z[4], z[5]), fminf(z[6], z[7])));
      const bool valid = (t < Lz);

      #pragma unroll
      for (int k = 0; k < 8; ++k) {
        cmax[k] += (z[k] == mx) ? z[k] : 0.0f;   // padded tail adds 0 -> harmless
        cmin[k] += (valid & (z[k] == mn)) ? 1 : 0;
      }
    }

    #pragma unroll
    for (int k = 0; k < 8; ++k) cmax[k] = wredf(cmax[k]);
    #pragma unroll
    for (int k = 0; k < 8; ++k) cmin[k] = wredi(cmin[k]);

    if (lane == 63) {
      float4 a0 = make_float4(cmax[0], cmax[1], cmax[2], cmax[3]);
      float4 a1 = make_float4(cmax[4], cmax[5], cmax[6], cmax[7]);
      float4 b0 = make_float4((float)cmin[0], (float)cmin[1],
                              (float)cmin[2], (float)cmin[3]);
      float4 b1 = make_float4((float)cmin[4], (float)cmin[5],
                              (float)cmin[6], (float)cmin[7]);
      float4* pm = (float4*)(outb + g * 8);
      pm[0] = a0; pm[1] = a1;
      float4* pn = (float4*)(outb + 256 + g * 8);
      pn[0] = b0; pn[1] = b1;
    }
  }
}

extern "C" void kernel_launch(void* const* d_in, const int* in_sizes, int n_in,
                              void* d_out, int out_size, void* d_ws, size_t ws_size,
                              hipStream_t stream) {
  const float* X = (const float*)d_in[0];   // (256,1,1024) f32
  const float* W = (const float*)d_in[1];   // (7,2,256,1,9) f32, normalized
  float* out = (float*)d_out;               // (256,7168) f32
  hydra_kernel<<<dim3(256 * 14), dim3(256), 0, stream>>>(X, W, out);
}

// Round 5
// 334.372 us; speedup vs baseline: 10.1563x; 10.1563x over previous
//
#include <hip/hip_runtime.h>

#define NPAD 256
#define LDSX 1536

// Sum across 64 lanes via DPP; valid result lands in lane 63. Pure VALU.
__device__ __forceinline__ float wredf(float x) {
  x += __int_as_float(__builtin_amdgcn_update_dpp(0, __float_as_int(x), 0x111, 0xf, 0xf, true)); // row_shr:1
  x += __int_as_float(__builtin_amdgcn_update_dpp(0, __float_as_int(x), 0x112, 0xf, 0xf, true)); // row_shr:2
  x += __int_as_float(__builtin_amdgcn_update_dpp(0, __float_as_int(x), 0x114, 0xf, 0xf, true)); // row_shr:4
  x += __int_as_float(__builtin_amdgcn_update_dpp(0, __float_as_int(x), 0x118, 0xf, 0xf, true)); // row_shr:8
  x += __int_as_float(__builtin_amdgcn_update_dpp(0, __float_as_int(x), 0x142, 0xa, 0xf, true)); // bcast15 rows 1,3
  x += __int_as_float(__builtin_amdgcn_update_dpp(0, __float_as_int(x), 0x143, 0xc, 0xf, true)); // bcast31 rows 2,3
  return x;
}
__device__ __forceinline__ int wredi(int x) {
  x += __builtin_amdgcn_update_dpp(0, x, 0x111, 0xf, 0xf, true);
  x += __builtin_amdgcn_update_dpp(0, x, 0x112, 0xf, 0xf, true);
  x += __builtin_amdgcn_update_dpp(0, x, 0x114, 0xf, 0xf, true);
  x += __builtin_amdgcn_update_dpp(0, x, 0x118, 0xf, 0xf, true);
  x += __builtin_amdgcn_update_dpp(0, x, 0x142, 0xa, 0xf, true);
  x += __builtin_amdgcn_update_dpp(0, x, 0x143, 0xc, 0xf, true);
  return x;
}

// Block = one (n, di, diff). 256 threads = 4 waves; each wave handles 8 groups,
// all 64 lanes cover 64 consecutive t positions per iteration (16 iters over 1024).
// Register budget is the whole game here: w[72] + ~2x(xv[9]+z[8]) live ≈ 130 VGPR.
__global__ void __launch_bounds__(256, 3) hydra_kernel(
    const float* __restrict__ X, const float* __restrict__ W,
    float* __restrict__ out) {
  __shared__ float xs[LDSX];

  const int b = blockIdx.x;
  const int n = b / 14;
  const int r = b - n * 14;          // di*2 + diff
  const int diff = r & 1;
  const int d = 1 << (r >> 1);       // dilation
  const int Lz = 1024 - diff;        // output length (1023 for diff branch)
  const float* xrow = X + n * 1024;
  const int tid = threadIdx.x;

  // Stage padded input row (zeros in [0,256) and [256+Lz,1536))
  for (int i = tid; i < LDSX; i += 256) {
    int t = i - NPAD;
    float v = 0.0f;
    if (t >= 0 && t < Lz) v = diff ? (xrow[t + 1] - xrow[t]) : xrow[t];
    xs[i] = v;
  }
  __syncthreads();

  const int lane = tid & 63;
  const int wv = tid >> 6;
  const float* wb = W + r * 2304;                    // (di,diff) filter bank: 256*9
  float* outb = out + (size_t)n * 7168 + r * 512;    // [cmax(256) | cmin(256)]

  for (int gp = 0; gp < 8; ++gp) {
    const int g = wv * 8 + gp;

    // 72 wave-uniform weights for this group's 8 kernels, via 18 float4 loads.
    // (g*72*4 = 288B-aligned offsets; W base is 16B-aligned.)
    float w[72];
    {
      const float4* w4 = (const float4*)(wb + g * 72);
      #pragma unroll
      for (int q = 0; q < 18; ++q) {
        float4 v = w4[q];
        w[q * 4 + 0] = v.x; w[q * 4 + 1] = v.y;
        w[q * 4 + 2] = v.z; w[q * 4 + 3] = v.w;
      }
    }

    float cmax[8];
    int cmin[8];
    #pragma unroll
    for (int k = 0; k < 8; ++k) { cmax[k] = 0.0f; cmin[k] = 0; }

    const int base0 = NPAD - 4 * d + lane;           // index of tap 0 at t=lane

    #pragma unroll 2
    for (int it = 0; it < 16; ++it) {
      const int t = it * 64 + lane;

      float xv[9];
      #pragma unroll
      for (int j = 0; j < 9; ++j) xv[j] = xs[base0 + it * 64 + j * d];

      float z[8];
      #pragma unroll
      for (int k = 0; k < 8; ++k) {
        float a = w[k * 9] * xv[0];
        #pragma unroll
        for (int j = 1; j < 9; ++j) a = fmaf(w[k * 9 + j], xv[j], a);
        z[k] = a;
      }

      const float mx = fmaxf(fmaxf(fmaxf(z[0], z[1]), fmaxf(z[2], z[3])),
                             fmaxf(fmaxf(z[4], z[5]), fmaxf(z[6], z[7])));
      const float mn = fminf(fminf(fminf(z[0], z[1]), fminf(z[2], z[3])),
                             fminf(fminf(z[4], z[5]), fminf(z[6], z[7])));
      const bool valid = (t < Lz);

      #pragma unroll
      for (int k = 0; k < 8; ++k) {
        cmax[k] += (z[k] == mx) ? z[k] : 0.0f;   // padded tail adds 0 -> harmless
        cmin[k] += (valid & (z[k] == mn)) ? 1 : 0;
      }
    }

    #pragma unroll
    for (int k = 0; k < 8; ++k) cmax[k] = wredf(cmax[k]);
    #pragma unroll
    for (int k = 0; k < 8; ++k) cmin[k] = wredi(cmin[k]);

    if (lane == 63) {
      float4 a0 = make_float4(cmax[0], cmax[1], cmax[2], cmax[3]);
      float4 a1 = make_float4(cmax[4], cmax[5], cmax[6], cmax[7]);
      float4 b0 = make_float4((float)cmin[0], (float)cmin[1],
                              (float)cmin[2], (float)cmin[3]);
      float4 b1 = make_float4((float)cmin[4], (float)cmin[5],
                              (float)cmin[6], (float)cmin[7]);
      float4* pm = (float4*)(outb + g * 8);
      pm[0] = a0; pm[1] = a1;
      float4* pn = (float4*)(outb + 256 + g * 8);
      pn[0] = b0; pn[1] = b1;
    }
  }
}

extern "C" void kernel_launch(void* const* d_in, const int* in_sizes, int n_in,
                              void* d_out, int out_size, void* d_ws, size_t ws_size,
                              hipStream_t stream) {
  const float* X = (const float*)d_in[0];   // (256,1,1024) f32
  const float* W = (const float*)d_in[1];   // (7,2,256,1,9) f32, normalized
  float* out = (float*)d_out;               // (256,7168) f32
  hydra_kernel<<<dim3(256 * 14), dim3(256), 0, stream>>>(X, W, out);
}